// Round 1
// baseline (337.982 us; speedup 1.0000x reference)
//
#include <hip/hip_runtime.h>
#include <hip/hip_bf16.h>

// out[i] = sum_j bit(x[i,j]) * 2^j,  bit = (sign(x)+1)/2 in {0, 0.5, 1}.
// N=4M, D=16. Pure streaming: 256 MB read + 16 MB write -> memory-bound,
// roofline ~43 us at 6.3 TB/s achievable HBM BW.
// One thread per row: 4x float4 loads (64 B/row), branchless sign map,
// coalesced scalar store.

__global__ __launch_bounds__(256) void bcd_reverse_kernel(
    const float* __restrict__ x, float* __restrict__ out, int n) {
  int i = blockIdx.x * blockDim.x + threadIdx.x;
  if (i >= n) return;

  const float4* row = reinterpret_cast<const float4*>(x + (size_t)i * 16);

  float acc = 0.0f;
  float w = 1.0f;
#pragma unroll
  for (int v = 0; v < 4; ++v) {
    float4 f = row[v];
    float vals[4] = {f.x, f.y, f.z, f.w};
#pragma unroll
    for (int k = 0; k < 4; ++k) {
      // jnp.sign semantics: +1 for >0, -1 for <0, 0 for ==0 (bit = 0.5)
      float s = (vals[k] > 0.0f) ? 1.0f : ((vals[k] < 0.0f) ? 0.0f : 0.5f);
      acc = fmaf(s, w, acc);
      w *= 2.0f;
    }
  }
  out[i] = acc;
}

extern "C" void kernel_launch(void* const* d_in, const int* in_sizes, int n_in,
                              void* d_out, int out_size, void* d_ws, size_t ws_size,
                              hipStream_t stream) {
  const float* x = (const float*)d_in[0];
  float* out = (float*)d_out;
  const int n = out_size;  // 4,000,000 rows; in_sizes[0] == n*16

  const int block = 256;
  const int grid = (n + block - 1) / block;
  bcd_reverse_kernel<<<grid, block, 0, stream>>>(x, out, n);
}

// Round 2
// 328.272 us; speedup vs baseline: 1.0296x; 1.0296x over previous
//
#include <hip/hip_runtime.h>
#include <hip/hip_bf16.h>

// out[i] = sum_j bit(x[i,j]) * 2^j,  bit = (sign(x)+1)/2 in {0, 0.5, 1}.
// N=4M, D=16. Memory-bound: 256 MB read + 16 MB write -> ~43 us floor @6.3 TB/s.
//
// R1 lesson: one-thread-per-row float4 loads stride 64 B across lanes ->
// each load instruction touches 64 cachelines using 16 B of each (~0.8 TB/s).
// Fix: one float4 per thread, contiguous across the wave (16 B/lane, 1 KB per
// load instruction). 4 lanes own one row; quad-reduce via __shfl_xor(1),(2);
// lane (t&3)==0 stores. All weights are powers of two -> exact fp32 math,
// identical numerics to the R1-passing kernel.

__global__ __launch_bounds__(256) void bcd_reverse_kernel(
    const float4* __restrict__ x4, float* __restrict__ out, int n4) {
  int t = blockIdx.x * blockDim.x + threadIdx.x;
  if (t >= n4) return;

  float4 f = x4[t];

  // jnp.sign semantics: bit = 1 for >0, 0 for <0, 0.5 for ==0.
  float b0 = (f.x > 0.0f) ? 1.0f : ((f.x < 0.0f) ? 0.0f : 0.5f);
  float b1 = (f.y > 0.0f) ? 1.0f : ((f.y < 0.0f) ? 0.0f : 0.5f);
  float b2 = (f.z > 0.0f) ? 1.0f : ((f.z < 0.0f) ? 0.0f : 0.5f);
  float b3 = (f.w > 0.0f) ? 1.0f : ((f.w < 0.0f) ? 0.0f : 0.5f);

  int q = t & 3;                               // quarter of the row
  float w0 = (float)(1u << (4 * q));           // 2^(4q): 1, 16, 256, 4096
  // (b0 + 2 b1 + 4 b2 + 8 b3) * 2^(4q): power-of-two scaling is exact.
  float partial = w0 * fmaf(8.0f, b3, fmaf(4.0f, b2, fmaf(2.0f, b1, b0)));

  // quad reduction: lanes {4r,4r+1,4r+2,4r+3} sum their partials
  partial += __shfl_xor(partial, 1);
  partial += __shfl_xor(partial, 2);

  if (q == 0) out[t >> 2] = partial;
}

extern "C" void kernel_launch(void* const* d_in, const int* in_sizes, int n_in,
                              void* d_out, int out_size, void* d_ws, size_t ws_size,
                              hipStream_t stream) {
  const float4* x4 = (const float4*)d_in[0];
  float* out = (float*)d_out;
  const int n4 = in_sizes[0] / 4;  // 16,000,000 float4s

  const int block = 256;
  const int grid = (n4 + block - 1) / block;  // 62,500 blocks
  bcd_reverse_kernel<<<grid, block, 0, stream>>>(x4, out, n4);
}

// Round 3
// 320.965 us; speedup vs baseline: 1.0530x; 1.0228x over previous
//
#include <hip/hip_runtime.h>
#include <hip/hip_bf16.h>

// out[i] = sum_j bit(x[i,j]) * 2^j,  bit = (sign(x)+1)/2 in {0, 0.5, 1}.
// N=4M rows, D=16 fp32. Memory-bound streaming: 256 MB read + 16 MB write
// -> ~41 us floor at the 6.6 TB/s the poison fills demonstrate.
//
// R2 lesson: one float4/thread (MLP=1) left latency-hiding to wave count.
// R3: 4 independent contiguous chunk loads per thread (4x MLP, 4x fewer
// waves), nontemporal load/store (pure stream, no reuse -> skip L2
// retention). Per wave each chunk's store covers exactly one 64 B line.
// All weights are powers of two -> exact fp32 math, same numerics as the
// passing R1/R2 kernels.

typedef float f32x4 __attribute__((ext_vector_type(4)));

__global__ __launch_bounds__(256) void bcd_reverse_kernel(
    const f32x4* __restrict__ x4, float* __restrict__ out, int n4) {
  const int tid = threadIdx.x;
  const size_t block_base = (size_t)blockIdx.x * 1024;  // 256 thr * 4 chunks

  // 4 independent loads, issued back-to-back before any use.
  f32x4 f[4];
  size_t idx[4];
#pragma unroll
  for (int c = 0; c < 4; ++c) {
    idx[c] = block_base + (size_t)c * 256 + tid;
    if (idx[c] < (size_t)n4)
      f[c] = __builtin_nontemporal_load(&x4[idx[c]]);
    else
      f[c] = (f32x4){0.5f, 0.5f, 0.5f, 0.5f};  // dead value, guarded store
  }

  const int q = tid & 3;                      // quarter of the row
  const float w0 = (float)(1u << (4 * q));    // 2^(4q): 1, 16, 256, 4096

#pragma unroll
  for (int c = 0; c < 4; ++c) {
    // jnp.sign semantics: bit = 1 for >0, 0 for <0, 0.5 for ==0.
    float b0 = (f[c].x > 0.0f) ? 1.0f : ((f[c].x < 0.0f) ? 0.0f : 0.5f);
    float b1 = (f[c].y > 0.0f) ? 1.0f : ((f[c].y < 0.0f) ? 0.0f : 0.5f);
    float b2 = (f[c].z > 0.0f) ? 1.0f : ((f[c].z < 0.0f) ? 0.0f : 0.5f);
    float b3 = (f[c].w > 0.0f) ? 1.0f : ((f[c].w < 0.0f) ? 0.0f : 0.5f);

    // (b0 + 2 b1 + 4 b2 + 8 b3) * 2^(4q): power-of-two scaling is exact.
    float partial = w0 * fmaf(8.0f, b3, fmaf(4.0f, b2, fmaf(2.0f, b1, b0)));

    // quad reduction across lanes {4r..4r+3}
    partial += __shfl_xor(partial, 1);
    partial += __shfl_xor(partial, 2);

    if (q == 0 && idx[c] < (size_t)n4)
      __builtin_nontemporal_store(partial, &out[idx[c] >> 2]);
  }
}

extern "C" void kernel_launch(void* const* d_in, const int* in_sizes, int n_in,
                              void* d_out, int out_size, void* d_ws, size_t ws_size,
                              hipStream_t stream) {
  const f32x4* x4 = (const f32x4*)d_in[0];
  float* out = (float*)d_out;
  const int n4 = in_sizes[0] / 4;  // 16,000,000 float4s

  const int block = 256;
  const int per_block = block * 4;                       // 1024 float4s/block
  const int grid = (n4 + per_block - 1) / per_block;     // 15,625 blocks
  bcd_reverse_kernel<<<grid, block, 0, stream>>>(x4, out, n4);
}